// Round 5
// baseline (352.273 us; speedup 1.0000x reference)
//
#include <hip/hip_runtime.h>
#include <stdint.h>

#define BATCH 2000000
#define NHID  14
#define NT    8                         // 16-row n-tiles per wave -> 128 rows/wave
#define NWAVE 16                        // 1024-thread block -> 4 waves/SIMD, one block/CU
#define ROWS_PER_BLOCK (NWAVE * 16 * NT)                         // 2048
#define NTILES ((BATCH + ROWS_PER_BLOCK - 1) / ROWS_PER_BLOCK)   // 977
#define NSLOT 118                       // 4 (L0) + 14*8 (hidden) + 2 (out) x32 A-fragments
#define LDS_BYTES (NSLOT * 64 * 16)     // 120832 B -> 1 block/CU

typedef float    v4f  __attribute__((ext_vector_type(4)));
typedef _Float16 v8h  __attribute__((ext_vector_type(8)));
typedef __fp16   v2p  __attribute__((ext_vector_type(2)));  // matches cvt_pkrtz return
typedef uint32_t v4u  __attribute__((ext_vector_type(4)));

// x32 MFMA layouts: A[m=lane&15][k=quad*8+j], B[k=quad*8+j][n=lane&15],
// C/D[row=quad*4+reg][col=lane&15].
// k-permutation: A's k-columns stored permuted so the next-layer B fragment is
// exactly the concatenation of two packed C tiles (no cross-lane ops).
// Slot kappa = 32*t' + 8*q + j holds actual feature kown(kappa):
//   s = 8*t' + j ; kown = 16*(s>>2) + 4*q + (s&3)
__device__ __forceinline__ int kown(int kappa) {
    int s = ((kappa >> 5) << 3) | (kappa & 7);
    int q = (kappa >> 3) & 3;
    return ((s >> 2) << 4) | (q * 4 + (s & 3));
}

__device__ __forceinline__ uint32_t pk(float a, float b) {      // v_cvt_pkrtz_f16_f32
    union { v2p v; uint32_t u; } c;
    c.v = __builtin_amdgcn_cvt_pkrtz(a, b);
    return c.u;
}
__device__ __forceinline__ uint32_t relu_pk(float a, float b) { // pkrtz + v_pk_max_f16
    v2p z = { (__fp16)0.0f, (__fp16)0.0f };
    union { v2p v; uint32_t u; } c;
    c.v = __builtin_amdgcn_cvt_pkrtz(a, b);
    c.v = __builtin_elementwise_max(c.v, z);
    return c.u;
}

// C tiles (4 x v4f) -> two x32 B fragments (relu + f16 pack). 16 VALU ops.
__device__ __forceinline__ void pack2(const v4f* acc, v8h* Bv) {
    union { v4u u; v8h h; } c0, c1;
    c0.u.x = relu_pk(acc[0][0], acc[0][1]);
    c0.u.y = relu_pk(acc[0][2], acc[0][3]);
    c0.u.z = relu_pk(acc[1][0], acc[1][1]);
    c0.u.w = relu_pk(acc[1][2], acc[1][3]);
    c1.u.x = relu_pk(acc[2][0], acc[2][1]);
    c1.u.y = relu_pk(acc[2][2], acc[2][3]);
    c1.u.z = relu_pk(acc[3][0], acc[3][1]);
    c1.u.w = relu_pk(acc[3][2], acc[3][3]);
    Bv[0] = c0.h;
    Bv[1] = c1.h;
}

extern "C" __global__ __launch_bounds__(1024, 4)
void mlp16(const float* __restrict__ x,
           const float* __restrict__ W0, const float* __restrict__ b0,
           const float* __restrict__ Wh, const float* __restrict__ bh,
           const float* __restrict__ Wo, const float* __restrict__ bo,
           float* __restrict__ out)
{
    extern __shared__ char smem_raw[];
    v8h* frag = (v8h*)smem_raw;         // [slot][lane], 16 B per lane

    const int tid  = threadIdx.x;
    const int lane = tid & 63;
    const int wv   = tid >> 6;
    const int l15  = lane & 15;
    const int quad = lane >> 4;

    // ------------- one-time weight staging (bias folded at k==50/16) -------------
    for (int s = wv; s < NSLOT; s += NWAVE) {
        float v[8];
        if (s < 4) {                    // layer 0: natural k, K=32 (16 real + bias@16)
            int m = s * 16 + l15;
            #pragma unroll
            for (int j = 0; j < 8; ++j) {
                int kap = quad * 8 + j;
                float val = 0.f;
                if (kap < 16)      { if (m < 50) val = W0[m * 16 + kap]; }
                else if (kap == 16){ if (m < 50) val = b0[m]; else if (m == 50) val = 1.f; }
                v[j] = val;
            }
        } else if (s < 116) {           // hidden: permuted k, bias col 50, identity row 50
            int h = s - 4, l = h >> 3, t = (h >> 2) & 1, mt = h & 3;
            int m = mt * 16 + l15;
            const float* W = Wh + l * 2500;
            #pragma unroll
            for (int j = 0; j < 8; ++j) {
                int ko = kown(t * 32 + quad * 8 + j);
                float val = 0.f;
                if (ko < 50)       { if (m < 50) val = W[m * 50 + ko]; }
                else if (ko == 50) { if (m < 50) val = bh[l * 50 + m]; else if (m == 50) val = 1.f; }
                v[j] = val;
            }
        } else {                        // output: permuted k, bias col 50, m<4
            int t = s - 116, m = l15;
            #pragma unroll
            for (int j = 0; j < 8; ++j) {
                int ko = kown(t * 32 + quad * 8 + j);
                float val = 0.f;
                if (m < 4) { if (ko < 50) val = Wo[m * 50 + ko]; else if (ko == 50) val = bo[m]; }
                v[j] = val;
            }
        }
        v8h fv;
        #pragma unroll
        for (int j = 0; j < 8; ++j) fv[j] = (_Float16)v[j];   // RNE
        frag[s * 64 + lane] = fv;
    }
    __syncthreads();                    // only barrier in the kernel

    // L0 / output A-fragments: register-resident
    v8h A0[4], Ao[2];
    #pragma unroll
    for (int mt = 0; mt < 4; ++mt) A0[mt] = frag[mt * 64 + lane];
    #pragma unroll
    for (int t = 0; t < 2; ++t)    Ao[t] = frag[(116 + t) * 64 + lane];

    const v4f z4 = (v4f){0.f, 0.f, 0.f, 0.f};   // persistent zero C operand

    for (int tile = blockIdx.x; tile < NTILES; tile += gridDim.x) {
        const int rowbase = tile * ROWS_PER_BLOCK + wv * (16 * NT);
        v8h Bv[NT][2];                  // activations, registers only

        // ---- layer 0 (K=32: 16 features + bias-one at kappa=16) ----
        #pragma unroll
        for (int nt = 0; nt < NT; ++nt) {
            int r  = rowbase + nt * 16 + l15;
            int rc = r < BATCH ? r : BATCH - 1;
            union { v4u u; v8h h; } bx;
            bx.u = (v4u){0u, 0u, 0u, 0u};
            if (quad < 2) {             // lanes 0-31: 2x16B loads, 1KB dense per 16 rows
                const float* xp = x + (size_t)rc * 16 + quad * 8;
                v4f xa = *(const v4f*)xp;
                v4f xb = *(const v4f*)(xp + 4);
                bx.u.x = pk(xa[0], xa[1]);
                bx.u.y = pk(xa[2], xa[3]);
                bx.u.z = pk(xb[0], xb[1]);
                bx.u.w = pk(xb[2], xb[3]);
            } else if (quad == 2) {
                bx.u.x = 0x3C00u;       // f16 1.0 at kappa=16 (bias slot)
            }
            v4f acc[4];
            #pragma unroll
            for (int mt = 0; mt < 4; ++mt)
                acc[mt] = __builtin_amdgcn_mfma_f32_16x16x32_f16(A0[mt], bx.h, z4, 0, 0, 0);
            pack2(acc, Bv[nt]);         // relu + pack: C tiles -> x32 B frags
        }

        // ---- 14 hidden layers: 8 x32 MFMA + 16 VALU per n-tile, no LDS for acts ----
        for (int l = 0; l < NHID; ++l) {
            v8h A[2][4];
            const v8h* ab = frag + (4 + l * 8) * 64 + lane;
            #pragma unroll
            for (int t = 0; t < 2; ++t)
                #pragma unroll
                for (int mt = 0; mt < 4; ++mt) A[t][mt] = ab[(t * 4 + mt) * 64]; // ds_read_b128
            #pragma unroll
            for (int nt = 0; nt < NT; ++nt) {
                v4f acc[4];
                #pragma unroll
                for (int mt = 0; mt < 4; ++mt)
                    acc[mt] = __builtin_amdgcn_mfma_f32_16x16x32_f16(A[0][mt], Bv[nt][0], z4, 0, 0, 0);
                #pragma unroll
                for (int mt = 0; mt < 4; ++mt)
                    acc[mt] = __builtin_amdgcn_mfma_f32_16x16x32_f16(A[1][mt], Bv[nt][1], acc[mt], 0, 0, 0);
                pack2(acc, Bv[nt]);
            }
        }

        // ---- output layer: 2 MFMA per n-tile; channels 0-3 = quad-0 regs 0-3 ----
        #pragma unroll
        for (int nt = 0; nt < NT; ++nt) {
            v4f acc = __builtin_amdgcn_mfma_f32_16x16x32_f16(Ao[0], Bv[nt][0], z4, 0, 0, 0);
            acc     = __builtin_amdgcn_mfma_f32_16x16x32_f16(Ao[1], Bv[nt][1], acc, 0, 0, 0);
            int r = rowbase + nt * 16 + l15;
            if (quad == 0 && r < BATCH)
                *(v4f*)(out + (size_t)r * 4) = acc;   // 16B store per row
        }
    }
}

extern "C" void kernel_launch(void* const* d_in, const int* in_sizes, int n_in,
                              void* d_out, int out_size, void* d_ws, size_t ws_size,
                              hipStream_t stream)
{
    (void)in_sizes; (void)n_in; (void)d_ws; (void)ws_size; (void)out_size;
    (void)hipFuncSetAttribute(reinterpret_cast<const void*>(mlp16),
                              hipFuncAttributeMaxDynamicSharedMemorySize, LDS_BYTES);
    mlp16<<<256, 1024, LDS_BYTES, stream>>>(
        (const float*)d_in[0], (const float*)d_in[1], (const float*)d_in[2],
        (const float*)d_in[3], (const float*)d_in[4], (const float*)d_in[5],
        (const float*)d_in[6], (float*)d_out);
}

// Round 6
// 316.183 us; speedup vs baseline: 1.1141x; 1.1141x over previous
//
#include <hip/hip_runtime.h>
#include <stdint.h>

#define BATCH 2000000
#define NHID  14
#define NT    4                         // 16-row n-tiles per wave -> 64 rows/wave
#define NWAVE 16                        // 1024-thread block: 4 waves/SIMD, 1 block/CU
#define ROWS_PER_BLOCK (NWAVE * 16 * NT)                         // 1024
#define NTILES ((BATCH + ROWS_PER_BLOCK - 1) / ROWS_PER_BLOCK)   // 1954
#define NSLOT 118                       // 4 (L0) + 14*8 (hidden) + 2 (out) x32 A-fragments
#define LDS_BYTES (NSLOT * 64 * 16)     // 120832 B

typedef float    v4f  __attribute__((ext_vector_type(4)));
typedef _Float16 v8h  __attribute__((ext_vector_type(8)));
typedef __fp16   v2p  __attribute__((ext_vector_type(2)));  // matches cvt_pkrtz return
typedef uint32_t v4u  __attribute__((ext_vector_type(4)));

// x32 MFMA layouts: A[m=lane&15][k=quad*8+j], B[k=quad*8+j][n=lane&15],
// C/D[row=quad*4+reg][col=lane&15].
// k-permutation: A's k-columns stored permuted so the next-layer B fragment is
// exactly the concatenation of two packed C tiles (no cross-lane ops).
// Slot kappa = 32*t' + 8*q + j holds actual feature kown(kappa):
//   s = 8*t' + j ; kown = 16*(s>>2) + 4*q + (s&3)
__device__ __forceinline__ int kown(int kappa) {
    int s = ((kappa >> 5) << 3) | (kappa & 7);
    int q = (kappa >> 3) & 3;
    return ((s >> 2) << 4) | (q * 4 + (s & 3));
}

__device__ __forceinline__ uint32_t pk(float a, float b) {      // v_cvt_pkrtz_f16_f32
    union { v2p v; uint32_t u; } c;
    c.v = __builtin_amdgcn_cvt_pkrtz(a, b);
    return c.u;
}
__device__ __forceinline__ uint32_t relu_pk(float a, float b) { // pkrtz + v_pk_max_f16
    v2p z = { (__fp16)0.0f, (__fp16)0.0f };
    union { v2p v; uint32_t u; } c;
    c.v = __builtin_amdgcn_cvt_pkrtz(a, b);
    c.v = __builtin_elementwise_max(c.v, z);
    return c.u;
}

// C tiles (4 x v4f) -> two x32 B fragments (relu + f16 pack). 16 VALU ops.
__device__ __forceinline__ void pack2(const v4f* acc, v8h* Bv) {
    union { v4u u; v8h h; } c0, c1;
    c0.u.x = relu_pk(acc[0][0], acc[0][1]);
    c0.u.y = relu_pk(acc[0][2], acc[0][3]);
    c0.u.z = relu_pk(acc[1][0], acc[1][1]);
    c0.u.w = relu_pk(acc[1][2], acc[1][3]);
    c1.u.x = relu_pk(acc[2][0], acc[2][1]);
    c1.u.y = relu_pk(acc[2][2], acc[2][3]);
    c1.u.z = relu_pk(acc[3][0], acc[3][1]);
    c1.u.w = relu_pk(acc[3][2], acc[3][3]);
    Bv[0] = c0.h;
    Bv[1] = c1.h;
}

extern "C" __global__ __launch_bounds__(1024, 4)
void mlp16(const float* __restrict__ x,
           const float* __restrict__ W0, const float* __restrict__ b0,
           const float* __restrict__ Wh, const float* __restrict__ bh,
           const float* __restrict__ Wo, const float* __restrict__ bo,
           float* __restrict__ out)
{
    extern __shared__ char smem_raw[];
    v8h* frag = (v8h*)smem_raw;         // [slot][lane], 16 B per lane

    const int tid  = threadIdx.x;
    const int lane = tid & 63;
    const int wv   = tid >> 6;
    const int l15  = lane & 15;
    const int quad = lane >> 4;

    // ------------- one-time weight staging (bias folded at k==50/16) -------------
    for (int s = wv; s < NSLOT; s += NWAVE) {
        float v[8];
        if (s < 4) {                    // layer 0: natural k, K=32 (16 real + bias@16)
            int m = s * 16 + l15;
            #pragma unroll
            for (int j = 0; j < 8; ++j) {
                int kap = quad * 8 + j;
                float val = 0.f;
                if (kap < 16)      { if (m < 50) val = W0[m * 16 + kap]; }
                else if (kap == 16){ if (m < 50) val = b0[m]; else if (m == 50) val = 1.f; }
                v[j] = val;
            }
        } else if (s < 116) {           // hidden: permuted k, bias col 50, identity row 50
            int h = s - 4, l = h >> 3, t = (h >> 2) & 1, mt = h & 3;
            int m = mt * 16 + l15;
            const float* W = Wh + l * 2500;
            #pragma unroll
            for (int j = 0; j < 8; ++j) {
                int ko = kown(t * 32 + quad * 8 + j);
                float val = 0.f;
                if (ko < 50)       { if (m < 50) val = W[m * 50 + ko]; }
                else if (ko == 50) { if (m < 50) val = bh[l * 50 + m]; else if (m == 50) val = 1.f; }
                v[j] = val;
            }
        } else {                        // output: permuted k, bias col 50, m<4
            int t = s - 116, m = l15;
            #pragma unroll
            for (int j = 0; j < 8; ++j) {
                int ko = kown(t * 32 + quad * 8 + j);
                float val = 0.f;
                if (m < 4) { if (ko < 50) val = Wo[m * 50 + ko]; else if (ko == 50) val = bo[m]; }
                v[j] = val;
            }
        }
        v8h fv;
        #pragma unroll
        for (int j = 0; j < 8; ++j) fv[j] = (_Float16)v[j];   // RNE
        frag[s * 64 + lane] = fv;
    }
    __syncthreads();                    // only barrier in the kernel

    const v4f z4 = (v4f){0.f, 0.f, 0.f, 0.f};   // zero C operand

    for (int tile = blockIdx.x; tile < NTILES; tile += gridDim.x) {
        const int rowbase = tile * ROWS_PER_BLOCK + wv * (16 * NT);
        v8h Bv[NT][2];                  // activations, registers only

        // ---- layer 0 (K=32: 16 features + bias-one at kappa=16) ----
        // A0 read from LDS per tile (keeps live-range short; ~8 tiles/block)
        {
            v8h A0[4];
            #pragma unroll
            for (int mt = 0; mt < 4; ++mt) A0[mt] = frag[mt * 64 + lane];
            #pragma unroll
            for (int nt = 0; nt < NT; ++nt) {
                int r  = rowbase + nt * 16 + l15;
                int rc = r < BATCH ? r : BATCH - 1;
                union { v4u u; v8h h; } bx;
                bx.u = (v4u){0u, 0u, 0u, 0u};
                if (quad < 2) {         // lanes 0-31: 2x16B loads, dense per 16 rows
                    const float* xp = x + (size_t)rc * 16 + quad * 8;
                    v4f xa = *(const v4f*)xp;
                    v4f xb = *(const v4f*)(xp + 4);
                    bx.u.x = pk(xa[0], xa[1]);
                    bx.u.y = pk(xa[2], xa[3]);
                    bx.u.z = pk(xb[0], xb[1]);
                    bx.u.w = pk(xb[2], xb[3]);
                } else if (quad == 2) {
                    bx.u.x = 0x3C00u;   // f16 1.0 at kappa=16 (bias slot)
                }
                v4f acc[4];
                #pragma unroll
                for (int mt = 0; mt < 4; ++mt)
                    acc[mt] = __builtin_amdgcn_mfma_f32_16x16x32_f16(A0[mt], bx.h, z4, 0, 0, 0);
                pack2(acc, Bv[nt]);     // relu + pack: C tiles -> x32 B frags
            }
        }

        // ---- 14 hidden layers: 8 x32 MFMA + 16 VALU per n-tile, no LDS for acts ----
        for (int l = 0; l < NHID; ++l) {
            v8h A[2][4];
            const v8h* ab = frag + (4 + l * 8) * 64 + lane;
            #pragma unroll
            for (int t = 0; t < 2; ++t)
                #pragma unroll
                for (int mt = 0; mt < 4; ++mt) A[t][mt] = ab[(t * 4 + mt) * 64]; // ds_read_b128
            #pragma unroll
            for (int nt = 0; nt < NT; ++nt) {
                v4f acc[4];
                #pragma unroll
                for (int mt = 0; mt < 4; ++mt)
                    acc[mt] = __builtin_amdgcn_mfma_f32_16x16x32_f16(A[0][mt], Bv[nt][0], z4, 0, 0, 0);
                #pragma unroll
                for (int mt = 0; mt < 4; ++mt)
                    acc[mt] = __builtin_amdgcn_mfma_f32_16x16x32_f16(A[1][mt], Bv[nt][1], acc[mt], 0, 0, 0);
                pack2(acc, Bv[nt]);
            }
        }

        // ---- output layer: 2 MFMA per n-tile; channels 0-3 = quad-0 regs 0-3 ----
        {
            v8h Ao[2];
            #pragma unroll
            for (int t = 0; t < 2; ++t) Ao[t] = frag[(116 + t) * 64 + lane];
            #pragma unroll
            for (int nt = 0; nt < NT; ++nt) {
                v4f acc = __builtin_amdgcn_mfma_f32_16x16x32_f16(Ao[0], Bv[nt][0], z4, 0, 0, 0);
                acc     = __builtin_amdgcn_mfma_f32_16x16x32_f16(Ao[1], Bv[nt][1], acc, 0, 0, 0);
                int r = rowbase + nt * 16 + l15;
                if (quad == 0 && r < BATCH)
                    *(v4f*)(out + (size_t)r * 4) = acc;   // 16B store per row
            }
        }
    }
}

extern "C" void kernel_launch(void* const* d_in, const int* in_sizes, int n_in,
                              void* d_out, int out_size, void* d_ws, size_t ws_size,
                              hipStream_t stream)
{
    (void)in_sizes; (void)n_in; (void)d_ws; (void)ws_size; (void)out_size;
    (void)hipFuncSetAttribute(reinterpret_cast<const void*>(mlp16),
                              hipFuncAttributeMaxDynamicSharedMemorySize, LDS_BYTES);
    mlp16<<<256, 1024, LDS_BYTES, stream>>>(
        (const float*)d_in[0], (const float*)d_in[1], (const float*)d_in[2],
        (const float*)d_in[3], (const float*)d_in[4], (const float*)d_in[5],
        (const float*)d_in[6], (float*)d_out);
}

// Round 7
// 314.941 us; speedup vs baseline: 1.1185x; 1.0039x over previous
//
#include <hip/hip_runtime.h>
#include <stdint.h>

#define BATCH 2000000
#define NHID  14
#define NT    6                         // 16-row n-tiles per wave -> 96 rows/wave
#define NWAVE 12                        // 768-thread block: 3 waves/SIMD (reg cap 170)
#define ROWS_PER_BLOCK (NWAVE * 16 * NT)                         // 1152
#define NTILES ((BATCH + ROWS_PER_BLOCK - 1) / ROWS_PER_BLOCK)   // 1737
#define NSLOT 118                       // 4 (L0) + 14*8 (hidden) + 2 (out) x32 A-fragments
#define LDS_BYTES (NSLOT * 64 * 16)     // 120832 B -> 1 block/CU

typedef float    v4f  __attribute__((ext_vector_type(4)));
typedef _Float16 v8h  __attribute__((ext_vector_type(8)));
typedef __fp16   v2p  __attribute__((ext_vector_type(2)));  // matches cvt_pkrtz return
typedef uint32_t v4u  __attribute__((ext_vector_type(4)));

// x32 MFMA layouts: A[m=lane&15][k=quad*8+j], B[k=quad*8+j][n=lane&15],
// C/D[row=quad*4+reg][col=lane&15].
// k-permutation: A's k-columns stored permuted so the next-layer B fragment is
// exactly the concatenation of two packed C tiles (no cross-lane ops).
// Slot kappa = 32*t' + 8*q + j holds actual feature kown(kappa):
//   s = 8*t' + j ; kown = 16*(s>>2) + 4*q + (s&3)
__device__ __forceinline__ int kown(int kappa) {
    int s = ((kappa >> 5) << 3) | (kappa & 7);
    int q = (kappa >> 3) & 3;
    return ((s >> 2) << 4) | (q * 4 + (s & 3));
}

__device__ __forceinline__ uint32_t pk(float a, float b) {      // v_cvt_pkrtz_f16_f32
    union { v2p v; uint32_t u; } c;
    c.v = __builtin_amdgcn_cvt_pkrtz(a, b);
    return c.u;
}
__device__ __forceinline__ uint32_t relu_pk(float a, float b) { // pkrtz + v_pk_max_f16
    v2p z = { (__fp16)0.0f, (__fp16)0.0f };
    union { v2p v; uint32_t u; } c;
    c.v = __builtin_amdgcn_cvt_pkrtz(a, b);
    c.v = __builtin_elementwise_max(c.v, z);
    return c.u;
}

// C tiles (4 x v4f) -> two x32 B fragments (relu + f16 pack). 16 VALU ops.
__device__ __forceinline__ void pack2(const v4f* acc, v8h* Bv) {
    union { v4u u; v8h h; } c0, c1;
    c0.u.x = relu_pk(acc[0][0], acc[0][1]);
    c0.u.y = relu_pk(acc[0][2], acc[0][3]);
    c0.u.z = relu_pk(acc[1][0], acc[1][1]);
    c0.u.w = relu_pk(acc[1][2], acc[1][3]);
    c1.u.x = relu_pk(acc[2][0], acc[2][1]);
    c1.u.y = relu_pk(acc[2][2], acc[2][3]);
    c1.u.z = relu_pk(acc[3][0], acc[3][1]);
    c1.u.w = relu_pk(acc[3][2], acc[3][3]);
    Bv[0] = c0.h;
    Bv[1] = c1.h;
}

extern "C" __global__ __launch_bounds__(768, 3)
void mlp16(const float* __restrict__ x,
           const float* __restrict__ W0, const float* __restrict__ b0,
           const float* __restrict__ Wh, const float* __restrict__ bh,
           const float* __restrict__ Wo, const float* __restrict__ bo,
           float* __restrict__ out)
{
    extern __shared__ char smem_raw[];
    v8h* frag = (v8h*)smem_raw;         // [slot][lane], 16 B per lane

    const int tid  = threadIdx.x;
    const int lane = tid & 63;
    const int wv   = tid >> 6;
    const int l15  = lane & 15;
    const int quad = lane >> 4;

    // ------------- one-time weight staging (bias folded at k==50/16) -------------
    for (int s = wv; s < NSLOT; s += NWAVE) {
        float v[8];
        if (s < 4) {                    // layer 0: natural k, K=32 (16 real + bias@16)
            int m = s * 16 + l15;
            #pragma unroll
            for (int j = 0; j < 8; ++j) {
                int kap = quad * 8 + j;
                float val = 0.f;
                if (kap < 16)      { if (m < 50) val = W0[m * 16 + kap]; }
                else if (kap == 16){ if (m < 50) val = b0[m]; else if (m == 50) val = 1.f; }
                v[j] = val;
            }
        } else if (s < 116) {           // hidden: permuted k, bias col 50, identity row 50
            int h = s - 4, l = h >> 3, t = (h >> 2) & 1, mt = h & 3;
            int m = mt * 16 + l15;
            const float* W = Wh + l * 2500;
            #pragma unroll
            for (int j = 0; j < 8; ++j) {
                int ko = kown(t * 32 + quad * 8 + j);
                float val = 0.f;
                if (ko < 50)       { if (m < 50) val = W[m * 50 + ko]; }
                else if (ko == 50) { if (m < 50) val = bh[l * 50 + m]; else if (m == 50) val = 1.f; }
                v[j] = val;
            }
        } else {                        // output: permuted k, bias col 50, m<4
            int t = s - 116, m = l15;
            #pragma unroll
            for (int j = 0; j < 8; ++j) {
                int ko = kown(t * 32 + quad * 8 + j);
                float val = 0.f;
                if (m < 4) { if (ko < 50) val = Wo[m * 50 + ko]; else if (ko == 50) val = bo[m]; }
                v[j] = val;
            }
        }
        v8h fv;
        #pragma unroll
        for (int j = 0; j < 8; ++j) fv[j] = (_Float16)v[j];   // RNE
        frag[s * 64 + lane] = fv;
    }
    __syncthreads();                    // only barrier in the kernel

    const v4f z4 = (v4f){0.f, 0.f, 0.f, 0.f};   // zero C operand

    for (int tile = blockIdx.x; tile < NTILES; tile += gridDim.x) {
        const int rowbase = tile * ROWS_PER_BLOCK + wv * (16 * NT);
        v8h Bv[NT][2];                  // activations, registers only

        // ---- layer 0 (K=32: 16 features + bias-one at kappa=16) ----
        {
            v8h A0[4];
            #pragma unroll
            for (int mt = 0; mt < 4; ++mt) A0[mt] = frag[mt * 64 + lane];
            #pragma unroll
            for (int nt = 0; nt < NT; ++nt) {
                int r  = rowbase + nt * 16 + l15;
                int rc = r < BATCH ? r : BATCH - 1;
                union { v4u u; v8h h; } bx;
                bx.u = (v4u){0u, 0u, 0u, 0u};
                if (quad < 2) {         // lanes 0-31: 2x16B loads, dense per 16 rows
                    const float* xp = x + (size_t)rc * 16 + quad * 8;
                    v4f xa = *(const v4f*)xp;
                    v4f xb = *(const v4f*)(xp + 4);
                    bx.u.x = pk(xa[0], xa[1]);
                    bx.u.y = pk(xa[2], xa[3]);
                    bx.u.z = pk(xb[0], xb[1]);
                    bx.u.w = pk(xb[2], xb[3]);
                } else if (quad == 2) {
                    bx.u.x = 0x3C00u;   // f16 1.0 at kappa=16 (bias slot)
                }
                v4f acc[4];
                #pragma unroll
                for (int mt = 0; mt < 4; ++mt)
                    acc[mt] = __builtin_amdgcn_mfma_f32_16x16x32_f16(A0[mt], bx.h, z4, 0, 0, 0);
                pack2(acc, Bv[nt]);     // relu + pack: C tiles -> x32 B frags
            }
        }

        // ---- 14 hidden layers: 8 x32 MFMA + 16 VALU per n-tile, no LDS for acts ----
        for (int l = 0; l < NHID; ++l) {
            v8h A[2][4];
            const v8h* ab = frag + (4 + l * 8) * 64 + lane;
            #pragma unroll
            for (int t = 0; t < 2; ++t)
                #pragma unroll
                for (int mt = 0; mt < 4; ++mt) A[t][mt] = ab[(t * 4 + mt) * 64]; // ds_read_b128
            #pragma unroll
            for (int nt = 0; nt < NT; ++nt) {
                v4f acc[4];
                #pragma unroll
                for (int mt = 0; mt < 4; ++mt)
                    acc[mt] = __builtin_amdgcn_mfma_f32_16x16x32_f16(A[0][mt], Bv[nt][0], z4, 0, 0, 0);
                #pragma unroll
                for (int mt = 0; mt < 4; ++mt)
                    acc[mt] = __builtin_amdgcn_mfma_f32_16x16x32_f16(A[1][mt], Bv[nt][1], acc[mt], 0, 0, 0);
                pack2(acc, Bv[nt]);
            }
        }

        // ---- output layer: 2 MFMA per n-tile; channels 0-3 = quad-0 regs 0-3 ----
        {
            v8h Ao[2];
            #pragma unroll
            for (int t = 0; t < 2; ++t) Ao[t] = frag[(116 + t) * 64 + lane];
            #pragma unroll
            for (int nt = 0; nt < NT; ++nt) {
                v4f acc = __builtin_amdgcn_mfma_f32_16x16x32_f16(Ao[0], Bv[nt][0], z4, 0, 0, 0);
                acc     = __builtin_amdgcn_mfma_f32_16x16x32_f16(Ao[1], Bv[nt][1], acc, 0, 0, 0);
                int r = rowbase + nt * 16 + l15;
                if (quad == 0 && r < BATCH)
                    *(v4f*)(out + (size_t)r * 4) = acc;   // 16B store per row
            }
        }
    }
}

extern "C" void kernel_launch(void* const* d_in, const int* in_sizes, int n_in,
                              void* d_out, int out_size, void* d_ws, size_t ws_size,
                              hipStream_t stream)
{
    (void)in_sizes; (void)n_in; (void)d_ws; (void)ws_size; (void)out_size;
    (void)hipFuncSetAttribute(reinterpret_cast<const void*>(mlp16),
                              hipFuncAttributeMaxDynamicSharedMemorySize, LDS_BYTES);
    mlp16<<<256, 768, LDS_BYTES, stream>>>(
        (const float*)d_in[0], (const float*)d_in[1], (const float*)d_in[2],
        (const float*)d_in[3], (const float*)d_in[4], (const float*)d_in[5],
        (const float*)d_in[6], (float*)d_out);
}